// Round 7
// baseline (232.323 us; speedup 1.0000x reference)
//
#include <hip/hip_runtime.h>
#include <hip/hip_bf16.h>

// BertCrf: B=64, S=512, H=768, L=9
// K1 fused, one block per (b, chunk of 8 steps):
//   phase E (all 4 waves): emissions, W in regs, DPP-16 reduce -> fsl4 partials (LDS)
//   barrier1; waves1-2 collapse fsl4 -> fsl2[8][12] (+bias); wave0 loads T into regs
//   barrier2; wave3 score partial; wave1 A0 (c==0); waves1-3 EXIT.
//   wave0 lanes 0-8: 8-step log-semiring product, row-per-lane, all in registers,
//   NO barriers / NO cross-lane on the chain. Writes Q[81].
// K2 combine: per b: fold 64 chunk matrices, sum score partials, atomic mean.
#define BB 64
#define SS 512
#define HH 768
#define LL 9
#define CL 8
#define NC (SS / CL)          // 64
#define NEG (-1e30f)

#define EXP2F(x) exp2f(x)     // v_exp_f32 (log2 domain)
#define LOG2F(x) __log2f(x)   // v_log_f32

static __device__ __forceinline__ float dot4(float4 a, float4 b) {
    return a.x * b.x + a.y * b.y + a.z * b.z + a.w * b.w;
}

static __device__ __forceinline__ float max9(const float* v) {
    float m1 = fmaxf(fmaxf(v[0], v[1]), v[2]);   // v_max3 chains
    float m2 = fmaxf(fmaxf(v[3], v[4]), v[5]);
    float m3 = fmaxf(fmaxf(v[6], v[7]), v[8]);
    return fmaxf(fmaxf(m1, m2), m3);
}

static __device__ __forceinline__ float sum9exp(const float* v, float mx) {
    float e0 = EXP2F(v[0] - mx), e1 = EXP2F(v[1] - mx), e2 = EXP2F(v[2] - mx);
    float e3 = EXP2F(v[3] - mx), e4 = EXP2F(v[4] - mx), e5 = EXP2F(v[5] - mx);
    float e6 = EXP2F(v[6] - mx), e7 = EXP2F(v[7] - mx), e8 = EXP2F(v[8] - mx);
    return ((e0 + e1) + (e2 + e3)) + (((e4 + e5) + (e6 + e7)) + e8);
}

template <int CTRL>
static __device__ __forceinline__ float dpp_add(float v) {
    return v + __int_as_float(
        __builtin_amdgcn_update_dpp(0, __float_as_int(v), CTRL, 0xF, 0xF, true));
}

// 16-lane-row sum, pure VALU pipe.
static __device__ __forceinline__ float group_sum16(float v) {
    v = dpp_add<0xB1>(v);    // quad_perm [1,0,3,2] == xor 1
    v = dpp_add<0x4E>(v);    // quad_perm [2,3,0,1] == xor 2
    v = dpp_add<0x124>(v);   // row_ror:4
    v = dpp_add<0x128>(v);   // row_ror:8
    return v;
}

static __device__ __forceinline__ float lds_sum4(const float* p) {
    float4 q = *(const float4*)p;
    return (q.x + q.y) + (q.z + q.w);
}

// ---------------- K1: fused ----------------
__global__ __launch_bounds__(256)
void fused_kernel(const float* __restrict__ hidden,
                  const float* __restrict__ W,
                  const float* __restrict__ bias,
                  const float* __restrict__ start_t,
                  const float* __restrict__ end_t,
                  const float* __restrict__ trans,
                  const int* __restrict__ labels,
                  const int* __restrict__ mask,
                  float* __restrict__ Q,      // [BB*NC][81]
                  float* __restrict__ A0,     // [BB][16]
                  float* __restrict__ Sc,     // [BB*NC]
                  float* __restrict__ out0) {
    const int bid  = blockIdx.x;
    const int b    = bid >> 6;                 // NC = 64
    const int c    = bid & (NC - 1);
    const int tid  = threadIdx.x;
    const int lane = tid & 63;
    const int wv   = tid >> 6;

    if (bid == 0 && tid == 0) out0[0] = 0.f;

    __shared__ float fsl4[CL][LL][4];          // emission group-partials
    __shared__ float fsl2[CL][12];             // collapsed emissions (+bias)

    const int bS     = b * SS;
    const int t_base = c * CL;
    const float INV_LN2 = 1.4426950408889634f;

    const int off   = (c == 0) ? 1 : 0;
    const int steps = CL - off;                // 7 or 8
    const int t0    = t_base + off;

    int na = 0;                                // active steps (mask monotone)
#pragma unroll
    for (int u = 0; u < CL; ++u)
        na += (u < steps && mask[bS + t0 + u] != 0) ? 1 : 0;

    // score-partial integer loads (wave 3), issued early
    int mt = 0, lc = 0, lp = 0, mnext = 0;
    const int t_sc = t_base + lane;
    if (wv == 3 && lane < CL) {
        mt    = mask[bS + t_sc];
        lc    = labels[bS + t_sc];
        lp    = (t_sc >= 1) ? labels[bS + t_sc - 1] : 0;
        mnext = (t_sc == SS - 1) ? 0 : mask[bS + t_sc + 1];
    }

    // ---- phase E: emissions (identical to round 5) ----
    float4 wreg[3][LL];
#pragma unroll
    for (int c3 = 0; c3 < 3; ++c3)
#pragma unroll
        for (int l = 0; l < LL; ++l)
            wreg[c3][l] = *(const float4*)(W + l * HH + c3 * 256 + (lane << 2));

    const float* hbase = hidden + ((size_t)bS + t_base) * HH;
    const int r0 = wv * 2, r1 = r0 + 1;
    const float4* h0p = (const float4*)(hbase + (size_t)r0 * HH);
    const float4* h1p = (const float4*)(hbase + (size_t)r1 * HH);
    float4 a0 = h0p[lane], a1 = h0p[64 + lane], a2 = h0p[128 + lane];
    float4 b0 = h1p[lane], b1 = h1p[64 + lane], b2 = h1p[128 + lane];

    float accA[LL], accB[LL];
#pragma unroll
    for (int l = 0; l < LL; ++l) {
        accA[l] = dot4(a0, wreg[0][l]) + dot4(a1, wreg[1][l]) + dot4(a2, wreg[2][l]);
        accB[l] = dot4(b0, wreg[0][l]) + dot4(b1, wreg[1][l]) + dot4(b2, wreg[2][l]);
    }

    const int g  = lane >> 4;
    const int sl = lane & 15;
    float selA = 0.f, selB = 0.f;
#pragma unroll
    for (int l = 0; l < LL; ++l) {
        float rA = group_sum16(accA[l]);
        float rB = group_sum16(accB[l]);
        if (sl == l) { selA = rA; selB = rB; }
    }
    if (sl < LL) {
        fsl4[r0][sl][g] = selA;
        fsl4[r1][sl][g] = selB;
    }
    __syncthreads();                           // barrier 1: fsl4 ready

    // ---- waves 1-2: collapse to fsl2 (+bias). wave 0: load T into registers ----
    float T2[LL][LL];                          // wave-0 only live range
    if (wv == 0) {
#pragma unroll
        for (int k = 0; k < LL; ++k)
#pragma unroll
            for (int j = 0; j < LL; ++j)
                T2[k][j] = trans[k * LL + j] * INV_LN2;
    } else if (wv <= 2) {
        const int local = tid - 64;
        if (local < CL * LL) {
            const int u  = local / LL;
            const int jj = local - u * LL;
            fsl2[u][jj] = lds_sum4(&fsl4[u][jj][0]) + bias[jj];
        }
    }
    __syncthreads();                           // barrier 2: fsl2 ready

    // ---- wave 3: score partial ----
    if (wv == 3 && lane < CL) {
        float sc = 0.f;
        if (t_sc >= 1 && mt) sc += trans[lp * LL + lc] + fsl2[lane][lc];
        if (t_sc == 0)       sc += start_t[lc] + fsl2[0][lc];
        if (mt && !mnext)    sc += end_t[lc];
#pragma unroll
        for (int o = 1; o < CL; o <<= 1) sc += __shfl_xor(sc, o);
        if (lane == 0) Sc[bid] = sc;
    }
    // ---- wave 1: A0 (c==0 blocks only) ----
    if (wv == 1 && c == 0 && lane < LL)
        A0[b * 16 + lane] = (start_t[lane] + fsl2[0][lane]) * INV_LN2;

    if (wv != 0) return;                       // waves 1-3 free their SIMD slots

    // ---- wave 0, lanes 0-8: 8-step product, row-per-lane, registers only ----
    const int i = lane;
    if (i >= LL) return;

    float P[LL];
#pragma unroll
    for (int j = 0; j < LL; ++j) P[j] = (i == j) ? 0.f : NEG;

#pragma unroll
    for (int s = 0; s < CL; ++s) {
        if (s < na) {                          // uniform scalar branch
            const float* fr = &fsl2[s + off][0];
            float f0 = fr[0], f1 = fr[1], f2 = fr[2], f3 = fr[3], f4 = fr[4];
            float f5 = fr[5], f6 = fr[6], f7 = fr[7], f8 = fr[8];
            float fj[LL] = {f0, f1, f2, f3, f4, f5, f6, f7, f8};
            float Pn[LL];
#pragma unroll
            for (int j = 0; j < LL; ++j) {
                float v[LL];
#pragma unroll
                for (int k = 0; k < LL; ++k) v[k] = P[k] + T2[k][j];
                const float mx  = max9(v);
                const float sum = sum9exp(v, mx);
                Pn[j] = mx + LOG2F(sum) + fj[j] * INV_LN2;
            }
#pragma unroll
            for (int j = 0; j < LL; ++j) P[j] = Pn[j];
        }
    }

    float* Qr = Q + (size_t)bid * (LL * LL) + i * LL;
#pragma unroll
    for (int j = 0; j < LL; ++j) Qr[j] = P[j];
}

// ---------------- K2: fold 64 chunks + score sum + atomic mean ----------------
__global__ __launch_bounds__(64, 1)
void combine_kernel(const float* __restrict__ Q,
                    const float* __restrict__ A0,
                    const float* __restrict__ Sc,
                    const float* __restrict__ end_t,
                    float* __restrict__ out) {
    const int b    = blockIdx.x;
    const int lane = threadIdx.x;
    const int j    = lane < LL ? lane : LL - 1;
    const float INV_LN2 = 1.4426950408889634f;
    const float LN2     = 0.6931471805599453f;

    float score = Sc[b * NC + lane];
#pragma unroll
    for (int o = 1; o < 64; o <<= 1) score += __shfl_xor(score, o);

    float alpha[LL];
#pragma unroll
    for (int k = 0; k < LL; ++k) alpha[k] = A0[b * 16 + k];

    const float* Qb = Q + (size_t)b * NC * (LL * LL);
    float qcol[LL], qnext[LL];
#pragma unroll
    for (int k = 0; k < LL; ++k) qnext[k] = Qb[k * LL + j];
    for (int cc = 0; cc < NC; ++cc) {
#pragma unroll
        for (int k = 0; k < LL; ++k) qcol[k] = qnext[k];
        if (cc + 1 < NC) {
            const float* Qn = Qb + (size_t)(cc + 1) * (LL * LL);
#pragma unroll
            for (int k = 0; k < LL; ++k) qnext[k] = Qn[k * LL + j];
        }
        float v[LL];
#pragma unroll
        for (int k = 0; k < LL; ++k) v[k] = alpha[k] + qcol[k];
        const float mx  = max9(v);
        const float sum = sum9exp(v, mx);
        const float anew = mx + LOG2F(sum);
#pragma unroll
        for (int k = 0; k < LL; ++k)
            alpha[k] = __uint_as_float(__builtin_amdgcn_readlane(__float_as_uint(anew), k));
    }

    float v[LL];
#pragma unroll
    for (int k = 0; k < LL; ++k) v[k] = alpha[k] + end_t[k] * INV_LN2;
    const float mx  = max9(v);
    const float sum = sum9exp(v, mx);
    const float log_den = (mx + LOG2F(sum)) * LN2;

    if (lane == 0)
        atomicAdd(out, (log_den - score) * (1.0f / BB));
}

extern "C" void kernel_launch(void* const* d_in, const int* in_sizes, int n_in,
                              void* d_out, int out_size, void* d_ws, size_t ws_size,
                              hipStream_t stream) {
    const float* hidden = (const float*)d_in[0];
    const float* W      = (const float*)d_in[1];
    const float* bias   = (const float*)d_in[2];
    const float* startT = (const float*)d_in[3];
    const float* endT   = (const float*)d_in[4];
    const float* trans  = (const float*)d_in[5];
    const int*   labels = (const int*)d_in[6];
    const int*   mask   = (const int*)d_in[7];

    float* Q  = (float*)d_ws;                      // 4096*81 fp32 = 1.33 MB
    float* A0 = Q + (size_t)BB * NC * LL * LL;     // 64*16 fp32
    float* Sc = A0 + BB * 16;                      // 4096 fp32

    fused_kernel<<<dim3(BB * NC), dim3(256), 0, stream>>>(
        hidden, W, bias, startT, endT, trans, labels, mask, Q, A0, Sc, (float*)d_out);
    combine_kernel<<<dim3(BB), dim3(64), 0, stream>>>(Q, A0, Sc, endT, (float*)d_out);
}